// Round 5
// baseline (446.395 us; speedup 1.0000x reference)
//
#include <hip/hip_runtime.h>

// Problem constants
constexpr int Bb = 4, Hh = 32, Wd = 256, Cc = 96;
constexpr int DI = 192, Nn = 16, Rr = 6, Kk = 2;
constexpr int LL = Hh * Wd;          // 8192
constexpr int ROWS = Bb * LL;        // 32768
constexpr int PROJ_C = 40;           // [0..5]=dts, pad, [8..23]=B, [24..39]=C
constexpr int G = 64;                // scan chunks
constexpr int CH = LL / G;           // 128 steps per chunk

static __device__ __forceinline__ float sigmoidf_(float v) {
  return 1.f / (1.f + __expf(-v));
}
static __device__ __forceinline__ float softplusf_(float v) {
  return v > 20.f ? v : __logf(1.f + __expf(v));
}

// ---------------------------------------------------------------------------
// Kernel 1: xz = x @ W_in^T  (32768 x 384, K=96). 64x64 tile, 4x4 reg tile.
// ---------------------------------------------------------------------------
__global__ __launch_bounds__(256) void k_xz(const float* __restrict__ x,
                                            const float* __restrict__ Win,
                                            float* __restrict__ xc,
                                            float* __restrict__ zbuf) {
  __shared__ float xt[24][66][4];
  __shared__ float wt[24][66][4];
  const int row0 = blockIdx.x * 64;
  const int col0 = blockIdx.y * 64;
  const int tid = threadIdx.x;

  for (int idx = tid; idx < 64 * 96; idx += 256) {
    int r = idx / 96, kkk = idx % 96;
    xt[kkk >> 2][r][kkk & 3] = x[(size_t)(row0 + r) * 96 + kkk];
    wt[kkk >> 2][r][kkk & 3] = Win[(size_t)(col0 + r) * 96 + kkk];
  }
  __syncthreads();

  const int tx = tid & 15, ty = tid >> 4;
  float acc[4][4] = {};
  for (int k4 = 0; k4 < 24; ++k4) {
    float4 a4[4], b4[4];
#pragma unroll
    for (int i = 0; i < 4; ++i) {
      a4[i] = *(const float4*)&xt[k4][ty + 16 * i][0];
      b4[i] = *(const float4*)&wt[k4][tx + 16 * i][0];
    }
#pragma unroll
    for (int r = 0; r < 4; ++r)
#pragma unroll
      for (int c = 0; c < 4; ++c) {
        acc[r][c] = fmaf(a4[r].x, b4[c].x, acc[r][c]);
        acc[r][c] = fmaf(a4[r].y, b4[c].y, acc[r][c]);
        acc[r][c] = fmaf(a4[r].z, b4[c].z, acc[r][c]);
        acc[r][c] = fmaf(a4[r].w, b4[c].w, acc[r][c]);
      }
  }

#pragma unroll
  for (int r = 0; r < 4; ++r) {
    int R = row0 + ty + 16 * r;
#pragma unroll
    for (int c = 0; c < 4; ++c) {
      int col = col0 + tx + 16 * c;
      if (col < DI)
        xc[(size_t)R * DI + col] = acc[r][c];
      else
        zbuf[(size_t)R * DI + (col - DI)] = acc[r][c];
    }
  }
}

// ---------------------------------------------------------------------------
// Kernel 2: depthwise 3x3 conv + bias + SiLU. Branch-free: thread = (b, h,
// 4-wide w tile, 4 channels). All 18 halo float4 loads issued unconditionally
// (clamped addresses, border values masked to 0) for deep MLP. Weights/bias
// staged transposed in LDS ([tap][d] -> ds_read_b128).
// ---------------------------------------------------------------------------
__global__ __launch_bounds__(256) void k_conv(const float* __restrict__ xc,
                                              const float* __restrict__ cw,
                                              const float* __restrict__ cbias,
                                              float* __restrict__ xf) {
  __shared__ float wl[9 * DI];   // [tap][d]
  __shared__ float bl[DI];
  const int tid = threadIdx.x;
  for (int v = tid; v < 9 * DI; v += 256) {
    int dd = v / 9, t = v % 9;
    wl[t * DI + dd] = cw[v];
  }
  if (tid < DI) bl[tid] = cbias[tid];
  __syncthreads();

  int gid = blockIdx.x * 256 + tid;  // (b, h, w4, d4), d4 fast
  int d4 = gid % 48;
  int rem = gid / 48;
  int w4 = rem % 64;
  int bh = rem / 64;
  int h = bh % Hh, b = bh / Hh;
  const int d0 = d4 * 4, w0 = w4 * 4;

  // 18 unconditional loads, masked at borders
  float4 c[3][6];
#pragma unroll
  for (int dr = 0; dr < 3; ++dr) {
    const int h2 = h + dr - 1;
    const bool hv = (unsigned)h2 < (unsigned)Hh;
    const int hc = hv ? h2 : h;
    const float* rp = xc + ((size_t)(b * LL + (hc << 8))) * DI + d0;
#pragma unroll
    for (int j = 0; j < 6; ++j) {
      const int wc = w0 - 1 + j;
      const bool wv = (unsigned)wc < (unsigned)Wd;
      const int wcc = wv ? wc : w0;
      float4 v = *(const float4*)&rp[(size_t)wcc * DI];
      const float m = (hv && wv) ? 1.f : 0.f;
      c[dr][j] = make_float4(v.x * m, v.y * m, v.z * m, v.w * m);
    }
  }

  float4 wv9[9];
#pragma unroll
  for (int t = 0; t < 9; ++t) wv9[t] = *(const float4*)&wl[t * DI + d0];
  const float4 bias4 = *(const float4*)&bl[d0];

#pragma unroll
  for (int wi = 0; wi < 4; ++wi) {
    float4 a = bias4;
#pragma unroll
    for (int dr = 0; dr < 3; ++dr)
#pragma unroll
      for (int dc = 0; dc < 3; ++dc) {
        const float4 vv = c[dr][wi + dc];
        const float4 ww = wv9[dr * 3 + dc];
        a.x = fmaf(vv.x, ww.x, a.x);
        a.y = fmaf(vv.y, ww.y, a.y);
        a.z = fmaf(vv.z, ww.z, a.z);
        a.w = fmaf(vv.w, ww.w, a.w);
      }
    float4 r;
    r.x = a.x * sigmoidf_(a.x);
    r.y = a.y * sigmoidf_(a.y);
    r.z = a.z * sigmoidf_(a.z);
    r.w = a.w * sigmoidf_(a.w);
    *(float4*)&xf[((size_t)(b * LL + (h << 8) + w0 + wi)) * DI + d0] = r;
  }
}

// ---------------------------------------------------------------------------
// Kernel 3: x_dbl projections. Register-tiled GEMM, 64l x 80s tile, 4x5 reg.
// ---------------------------------------------------------------------------
__global__ __launch_bounds__(256) void k_proj(const float* __restrict__ xf,
                                              const float* __restrict__ xpw,
                                              float* __restrict__ proj) {
  __shared__ float smem[5376];     // As[32][68] | Ws[32][84]; reused as res[64][84]
  float* As = smem;
  float* Ws = smem + 32 * 68;
  const int tid = threadIdx.x;
  const int row0 = blockIdx.x * 64;
  const int b = row0 >> 13;
  const int l0 = row0 & (LL - 1);
  const int tx = tid & 15;
  const int ty = tid >> 4;
  float acc[4][5] = {};

  for (int kc = 0; kc < 6; ++kc) {
    const int d0 = kc * 32;
    __syncthreads();
    for (int v = tid; v < 512; v += 256) {
      const int l = v >> 3, dk4 = v & 7;
      const float4 xv =
          *(const float4*)&xf[((size_t)b * LL + l0 + l) * DI + d0 + dk4 * 4];
      As[(dk4 * 4 + 0) * 68 + l] = xv.x;
      As[(dk4 * 4 + 1) * 68 + l] = xv.y;
      As[(dk4 * 4 + 2) * 68 + l] = xv.z;
      As[(dk4 * 4 + 3) * 68 + l] = xv.w;
    }
    for (int v = tid; v < 640; v += 256) {
      const int s = v >> 3, dk4 = v & 7;
      const int k = s / 40, off = s % 40;
      float4 wv = make_float4(0.f, 0.f, 0.f, 0.f);
      if (off < 6 || off >= 8) {
        const int c = off < 6 ? off : off - 2;
        wv = *(const float4*)&xpw[(size_t)(k * 38 + c) * DI + d0 + dk4 * 4];
      }
      Ws[(dk4 * 4 + 0) * 84 + s] = wv.x;
      Ws[(dk4 * 4 + 1) * 84 + s] = wv.y;
      Ws[(dk4 * 4 + 2) * 84 + s] = wv.z;
      Ws[(dk4 * 4 + 3) * 84 + s] = wv.w;
    }
    __syncthreads();
    for (int dk = 0; dk < 32; ++dk) {
      const float4 a4 = *(const float4*)&As[dk * 68 + ty * 4];
      float w[5];
#pragma unroll
      for (int j = 0; j < 5; ++j) w[j] = Ws[dk * 84 + tx * 5 + j];
      const float av[4] = {a4.x, a4.y, a4.z, a4.w};
#pragma unroll
      for (int i = 0; i < 4; ++i)
#pragma unroll
        for (int j = 0; j < 5; ++j)
          acc[i][j] = fmaf(av[i], w[j], acc[i][j]);
    }
  }

  __syncthreads();
  float* res = smem;  // [64][84]
#pragma unroll
  for (int i = 0; i < 4; ++i)
#pragma unroll
    for (int j = 0; j < 5; ++j)
      res[(ty * 4 + i) * 84 + tx * 5 + j] = acc[i][j];
  __syncthreads();
#pragma unroll
  for (int k = 0; k < 2; ++k) {
    float* dst = proj + ((size_t)(b * Kk + k) * LL + l0) * PROJ_C;
    for (int v = tid; v < 640; v += 256) {
      const int l = v / 10, q = v % 10;
      *(float4*)&dst[l * PROJ_C + q * 4] =
          *(const float4*)&res[l * 84 + k * 40 + q * 4];
    }
  }
}

// ---------------------------------------------------------------------------
// Kernel 4: delta[b,k,l,d] = softplus(dts_r . dtw + bias), float4 over d.
// ---------------------------------------------------------------------------
__global__ __launch_bounds__(256) void k_delta(const float* __restrict__ proj,
                                               const float* __restrict__ dtw_,
                                               const float* __restrict__ dtb_,
                                               float* __restrict__ delta) {
  int gid = blockIdx.x * 256 + threadIdx.x;
  int d4 = gid % 48;
  int rem = gid / 48;
  int l = rem % LL;
  int bk = rem / LL;
  int k = bk & 1;
  const float* pr = proj + (size_t)(bk * LL + l) * PROJ_C;
  float p[6];
#pragma unroll
  for (int r = 0; r < 6; ++r) p[r] = pr[r];
  float4 res;
#pragma unroll
  for (int j = 0; j < 4; ++j) {
    int kd = k * DI + d4 * 4 + j;
    const float* w6 = dtw_ + (size_t)kd * 6;
    float draw = dtb_[kd];
#pragma unroll
    for (int r = 0; r < 6; ++r) draw = fmaf(p[r], w6[r], draw);
    ((float*)&res)[j] = softplusf_(draw);
  }
  *(float4*)&delta[(size_t)(bk * LL + l) * DI + d4 * 4] = res;
}

// ---------------------------------------------------------------------------
// Scan kernels. Both directions merged into one launch (runtime kd decode)
// for 2x occupancy. PASS 1: hend/Pst (disjoint by bk -> race-free).
// PASS 3: y zero-initialized, both directions atomicAdd (fp32 add of two
// contributions is order-independent bitwise).
// ---------------------------------------------------------------------------
template <int PASS>
__global__ __launch_bounds__(256) void k_scan(
    const float* __restrict__ delta, const float* __restrict__ proj,
    const float* __restrict__ xf, const float* __restrict__ Alog,
    const float* __restrict__ Dsv, const float* __restrict__ hinit,
    float* __restrict__ hend, float* __restrict__ Pst,
    float* __restrict__ yout) {
  const int tid = threadIdx.x;
  const int sub = tid & 3, gi = tid >> 2;
  int rest = blockIdx.x;
  const int kdir = rest & 1;  rest >>= 1;
  const int dt3 = rest % 3;   rest /= 3;
  const int g = rest % G;
  const int b = rest / G;
  const int d = dt3 * 64 + gi;
  const int kd = kdir * DI + d;
  const int bk = b * Kk + kdir;

  float A[4];
#pragma unroll
  for (int i = 0; i < 4; ++i) A[i] = -__expf(Alog[kd * 16 + sub * 4 + i]);

  const size_t gidx = (((size_t)(bk * G + g)) * DI + d) * Nn + sub * 4;
  float h[4];
  if (PASS == 1) {
    h[0] = h[1] = h[2] = h[3] = 0.f;
  } else {
    float4 h4 = *(const float4*)&hinit[gidx];
    h[0] = h4.x; h[1] = h4.y; h[2] = h4.z; h[3] = h4.w;
  }
  const float Dv = (PASS == 3) ? Dsv[kd] : 0.f;

  const int stp = kdir ? -1 : 1;
  const int dstp = stp * DI, pstp = stp * PROJ_C;
  const int l_start = kdir ? (LL - 1 - g * CH) : (g * CH);
  const float* dp = delta + ((size_t)bk * LL + l_start) * DI + d;
  const float* up = xf + ((size_t)b * LL + l_start) * DI + d;
  const float* pp = proj + ((size_t)bk * LL + l_start) * PROJ_C + 8 + sub * 4;
  const size_t ybase = ((size_t)b * DI + d) * LL;

  float dsum = 0.f, ybuf = 0.f;
#pragma unroll 4
  for (int t = 0; t < CH; ++t) {
    const float dlt = *dp;
    const float u = *up;
    const float4 Bv = *(const float4*)pp;
    const float du = dlt * u;
    if (PASS == 1) {
#pragma unroll
      for (int i = 0; i < 4; ++i)
        h[i] = fmaf(__expf(dlt * A[i]), h[i], du * ((const float*)&Bv)[i]);
      dsum += dlt;
    } else {
      const float4 Cv = *(const float4*)(pp + 16);
      float yp = 0.f;
#pragma unroll
      for (int i = 0; i < 4; ++i) {
        h[i] = fmaf(__expf(dlt * A[i]), h[i], du * ((const float*)&Bv)[i]);
        yp = fmaf(h[i], ((const float*)&Cv)[i], yp);
      }
      yp += __shfl_xor(yp, 1, 64);
      yp += __shfl_xor(yp, 2, 64);
      const float yt = fmaf(u, Dv, yp);
      ybuf = ((t & 3) == sub) ? yt : ybuf;
      if ((t & 3) == 3) {
        const int tau = g * CH + (t & ~3) + sub;
        const int lp = kdir ? (LL - 1 - tau) : tau;
        atomicAdd(&yout[ybase + lp], ybuf);
      }
    }
    dp += dstp; up += dstp; pp += pstp;
  }
  if (PASS == 1) {
    float4 hv = make_float4(h[0], h[1], h[2], h[3]);
    float4 pv = make_float4(__expf(A[0] * dsum), __expf(A[1] * dsum),
                            __expf(A[2] * dsum), __expf(A[3] * dsum));
    *(float4*)&hend[gidx] = hv;
    *(float4*)&Pst[gidx] = pv;
  }
}

// Pass 2: combine chunk summaries sequentially per (b,k,d,n).
__global__ __launch_bounds__(256) void k_scan2(const float* __restrict__ hend,
                                               const float* __restrict__ Pst,
                                               float* __restrict__ hini) {
  int idx = blockIdx.x * 256 + threadIdx.x;
  int n = idx & 15;
  int rem = idx >> 4;
  int d = rem % DI;
  int bk = rem / DI;
  float carry = 0.f;
  for (int g = 0; g < G; ++g) {
    size_t a = (((size_t)(bk * G + g)) * DI + d) * Nn + n;
    float hv = hend[a], pv = Pst[a];
    hini[a] = carry;
    carry = fmaf(pv, carry, hv);
  }
}

// ---------------------------------------------------------------------------
// Kernel 7: out[l,c] = sum_d (y[b,d,l]*silu(z[b,l,d])) * Wout[c,d]
// Register-tiled GEMM: 128l x 96c block tile, K chunked by 32, 4x12 reg tile.
// ---------------------------------------------------------------------------
__global__ __launch_bounds__(256) void k_out(const float* __restrict__ y,
                                             const float* __restrict__ zbuf,
                                             const float* __restrict__ Wout,
                                             float* __restrict__ out) {
  __shared__ float As[32][132];
  __shared__ float Ws[32][100];
  const int tid = threadIdx.x;
  const int row0 = blockIdx.x * 128;
  const int b = row0 >> 13;
  const int l0 = row0 & (LL - 1);
  const int tx = tid & 7;
  const int ty = tid >> 3;
  float acc[4][12] = {};

  for (int kc = 0; kc < 6; ++kc) {
    const int d0 = kc * 32;
    __syncthreads();
    for (int v = tid; v < 1024; v += 256) {
      const int l = v >> 3, dk4 = v & 7;
      const float4 zv = *(const float4*)&zbuf[((size_t)b * LL + l0 + l) * DI +
                                              d0 + dk4 * 4];
      As[dk4 * 4 + 0][l] = zv.x * sigmoidf_(zv.x);
      As[dk4 * 4 + 1][l] = zv.y * sigmoidf_(zv.y);
      As[dk4 * 4 + 2][l] = zv.z * sigmoidf_(zv.z);
      As[dk4 * 4 + 3][l] = zv.w * sigmoidf_(zv.w);
    }
    for (int v = tid; v < 768; v += 256) {
      const int c = v >> 3, dk4 = v & 7;
      const float4 wv = *(const float4*)&Wout[(size_t)c * DI + d0 + dk4 * 4];
      Ws[dk4 * 4 + 0][c] = wv.x;
      Ws[dk4 * 4 + 1][c] = wv.y;
      Ws[dk4 * 4 + 2][c] = wv.z;
      Ws[dk4 * 4 + 3][c] = wv.w;
    }
    __syncthreads();
    for (int v = tid; v < 1024; v += 256) {
      const int dk = v >> 5, l4 = v & 31;
      const float4 yv =
          *(const float4*)&y[((size_t)b * DI + d0 + dk) * LL + l0 + l4 * 4];
      As[dk][l4 * 4 + 0] *= yv.x;
      As[dk][l4 * 4 + 1] *= yv.y;
      As[dk][l4 * 4 + 2] *= yv.z;
      As[dk][l4 * 4 + 3] *= yv.w;
    }
    __syncthreads();
    for (int dk = 0; dk < 32; ++dk) {
      const float4 a4 = *(const float4*)&As[dk][ty * 4];
      const float4 w0 = *(const float4*)&Ws[dk][tx * 12];
      const float4 w1 = *(const float4*)&Ws[dk][tx * 12 + 4];
      const float4 w2 = *(const float4*)&Ws[dk][tx * 12 + 8];
      const float av[4] = {a4.x, a4.y, a4.z, a4.w};
      const float wv[12] = {w0.x, w0.y, w0.z, w0.w, w1.x, w1.y,
                            w1.z, w1.w, w2.x, w2.y, w2.z, w2.w};
#pragma unroll
      for (int i = 0; i < 4; ++i)
#pragma unroll
        for (int j = 0; j < 12; ++j)
          acc[i][j] = fmaf(av[i], wv[j], acc[i][j]);
    }
  }

#pragma unroll
  for (int i = 0; i < 4; ++i) {
    float* op = out + ((size_t)b * LL + l0 + ty * 4 + i) * 96 + tx * 12;
    *(float4*)(op + 0) = make_float4(acc[i][0], acc[i][1], acc[i][2], acc[i][3]);
    *(float4*)(op + 4) = make_float4(acc[i][4], acc[i][5], acc[i][6], acc[i][7]);
    *(float4*)(op + 8) = make_float4(acc[i][8], acc[i][9], acc[i][10], acc[i][11]);
  }
}

// ---------------------------------------------------------------------------
extern "C" void kernel_launch(void* const* d_in, const int* in_sizes, int n_in,
                              void* d_out, int out_size, void* d_ws,
                              size_t ws_size, hipStream_t stream) {
  const float* x    = (const float*)d_in[0];
  const float* Win  = (const float*)d_in[1];
  const float* cw   = (const float*)d_in[2];
  const float* cb   = (const float*)d_in[3];
  const float* xpw  = (const float*)d_in[4];
  const float* dtw  = (const float*)d_in[5];
  const float* dtb  = (const float*)d_in[6];
  const float* Alog = (const float*)d_in[7];
  const float* Dsv  = (const float*)d_in[8];
  const float* Wout = (const float*)d_in[9];
  float* out = (float*)d_out;

  float* ws = (float*)d_ws;
  size_t o = 0;
  float* zbuf  = ws + o;  o += (size_t)ROWS * DI;                 // 25.2 MB
  float* xf    = ws + o;  o += (size_t)ROWS * DI;                 // 25.2 MB
  float* proj  = ws + o;  o += (size_t)Bb * Kk * LL * PROJ_C;     // 10.5 MB
  float* delta = ws + o;  o += (size_t)Bb * Kk * LL * DI;         // 50.3 MB
  const size_t hsz = (size_t)Bb * Kk * G * DI * Nn;
  float* hend = ws + o;  o += hsz;
  float* Pst  = ws + o;  o += hsz;
  float* hini = ws + o;  o += hsz;
  float* y    = ws + o;  o += (size_t)Bb * DI * LL;               // 25.2 MB
  float* xc   = y;  // alias: xc dead after conv, before y is zeroed/written

  k_xz<<<dim3(ROWS / 64, 6), 256, 0, stream>>>(x, Win, xc, zbuf);
  k_conv<<<dim3((Bb * Hh * 64 * 48) / 256), 256, 0, stream>>>(xc, cw, cb, xf);
  // y must be zero for the atomic-accumulating PASS 3 (xc alias now dead)
  hipMemsetAsync(y, 0, (size_t)Bb * DI * LL * sizeof(float), stream);
  k_proj<<<dim3(ROWS / 64), 256, 0, stream>>>(xf, xpw, proj);
  k_delta<<<dim3((Bb * Kk * LL * 48) / 256), 256, 0, stream>>>(proj, dtw, dtb,
                                                               delta);
  k_scan<1><<<dim3(Bb * G * 3 * 2), 256, 0, stream>>>(
      delta, proj, xf, Alog, Dsv, nullptr, hend, Pst, nullptr);
  k_scan2<<<dim3((Bb * Kk * DI * Nn) / 256), 256, 0, stream>>>(hend, Pst,
                                                               hini);
  k_scan<3><<<dim3(Bb * G * 3 * 2), 256, 0, stream>>>(
      delta, proj, xf, Alog, Dsv, hini, nullptr, nullptr, y);
  k_out<<<dim3(ROWS / 128), 256, 0, stream>>>(y, zbuf, Wout, out);
}

// Round 6
// 356.147 us; speedup vs baseline: 1.2534x; 1.2534x over previous
//
#include <hip/hip_runtime.h>

// Problem constants
constexpr int Bb = 4, Hh = 32, Wd = 256, Cc = 96;
constexpr int DI = 192, Nn = 16, Rr = 6, Kk = 2;
constexpr int LL = Hh * Wd;          // 8192
constexpr int ROWS = Bb * LL;        // 32768
constexpr int PROJ_C = 40;           // [0..5]=dts, pad, [8..23]=B, [24..39]=C
constexpr int G = 128;               // scan chunks
constexpr int CH = LL / G;           // 64 steps per chunk

static __device__ __forceinline__ float sigmoidf_(float v) {
  return 1.f / (1.f + __expf(-v));
}
static __device__ __forceinline__ float softplusf_(float v) {
  return v > 20.f ? v : __logf(1.f + __expf(v));
}

// ---------------------------------------------------------------------------
// Kernel 1: xz = x @ W_in^T  (32768 x 384, K=96). 64x64 tile, 4x4 reg tile.
// ---------------------------------------------------------------------------
__global__ __launch_bounds__(256) void k_xz(const float* __restrict__ x,
                                            const float* __restrict__ Win,
                                            float* __restrict__ xc,
                                            float* __restrict__ zbuf) {
  __shared__ float xt[24][66][4];
  __shared__ float wt[24][66][4];
  const int row0 = blockIdx.x * 64;
  const int col0 = blockIdx.y * 64;
  const int tid = threadIdx.x;

  for (int idx = tid; idx < 64 * 96; idx += 256) {
    int r = idx / 96, kkk = idx % 96;
    xt[kkk >> 2][r][kkk & 3] = x[(size_t)(row0 + r) * 96 + kkk];
    wt[kkk >> 2][r][kkk & 3] = Win[(size_t)(col0 + r) * 96 + kkk];
  }
  __syncthreads();

  const int tx = tid & 15, ty = tid >> 4;
  float acc[4][4] = {};
  for (int k4 = 0; k4 < 24; ++k4) {
    float4 a4[4], b4[4];
#pragma unroll
    for (int i = 0; i < 4; ++i) {
      a4[i] = *(const float4*)&xt[k4][ty + 16 * i][0];
      b4[i] = *(const float4*)&wt[k4][tx + 16 * i][0];
    }
#pragma unroll
    for (int r = 0; r < 4; ++r)
#pragma unroll
      for (int c = 0; c < 4; ++c) {
        acc[r][c] = fmaf(a4[r].x, b4[c].x, acc[r][c]);
        acc[r][c] = fmaf(a4[r].y, b4[c].y, acc[r][c]);
        acc[r][c] = fmaf(a4[r].z, b4[c].z, acc[r][c]);
        acc[r][c] = fmaf(a4[r].w, b4[c].w, acc[r][c]);
      }
  }

#pragma unroll
  for (int r = 0; r < 4; ++r) {
    int R = row0 + ty + 16 * r;
#pragma unroll
    for (int c = 0; c < 4; ++c) {
      int col = col0 + tx + 16 * c;
      if (col < DI)
        xc[(size_t)R * DI + col] = acc[r][c];
      else
        zbuf[(size_t)R * DI + (col - DI)] = acc[r][c];
    }
  }
}

// ---------------------------------------------------------------------------
// Kernel 2: depthwise 3x3 conv + bias + SiLU. Branch-free, 18 unconditional
// masked halo loads, weights transposed in LDS.
// ---------------------------------------------------------------------------
__global__ __launch_bounds__(256) void k_conv(const float* __restrict__ xc,
                                              const float* __restrict__ cw,
                                              const float* __restrict__ cbias,
                                              float* __restrict__ xf) {
  __shared__ float wl[9 * DI];   // [tap][d]
  __shared__ float bl[DI];
  const int tid = threadIdx.x;
  for (int v = tid; v < 9 * DI; v += 256) {
    int dd = v / 9, t = v % 9;
    wl[t * DI + dd] = cw[v];
  }
  if (tid < DI) bl[tid] = cbias[tid];
  __syncthreads();

  int gid = blockIdx.x * 256 + tid;  // (b, h, w4, d4), d4 fast
  int d4 = gid % 48;
  int rem = gid / 48;
  int w4 = rem % 64;
  int bh = rem / 64;
  int h = bh % Hh, b = bh / Hh;
  const int d0 = d4 * 4, w0 = w4 * 4;

  float4 c[3][6];
#pragma unroll
  for (int dr = 0; dr < 3; ++dr) {
    const int h2 = h + dr - 1;
    const bool hv = (unsigned)h2 < (unsigned)Hh;
    const int hc = hv ? h2 : h;
    const float* rp = xc + ((size_t)(b * LL + (hc << 8))) * DI + d0;
#pragma unroll
    for (int j = 0; j < 6; ++j) {
      const int wc = w0 - 1 + j;
      const bool wv = (unsigned)wc < (unsigned)Wd;
      const int wcc = wv ? wc : w0;
      float4 v = *(const float4*)&rp[(size_t)wcc * DI];
      const float m = (hv && wv) ? 1.f : 0.f;
      c[dr][j] = make_float4(v.x * m, v.y * m, v.z * m, v.w * m);
    }
  }

  float4 wv9[9];
#pragma unroll
  for (int t = 0; t < 9; ++t) wv9[t] = *(const float4*)&wl[t * DI + d0];
  const float4 bias4 = *(const float4*)&bl[d0];

#pragma unroll
  for (int wi = 0; wi < 4; ++wi) {
    float4 a = bias4;
#pragma unroll
    for (int dr = 0; dr < 3; ++dr)
#pragma unroll
      for (int dc = 0; dc < 3; ++dc) {
        const float4 vv = c[dr][wi + dc];
        const float4 ww = wv9[dr * 3 + dc];
        a.x = fmaf(vv.x, ww.x, a.x);
        a.y = fmaf(vv.y, ww.y, a.y);
        a.z = fmaf(vv.z, ww.z, a.z);
        a.w = fmaf(vv.w, ww.w, a.w);
      }
    float4 r;
    r.x = a.x * sigmoidf_(a.x);
    r.y = a.y * sigmoidf_(a.y);
    r.z = a.z * sigmoidf_(a.z);
    r.w = a.w * sigmoidf_(a.w);
    *(float4*)&xf[((size_t)(b * LL + (h << 8) + w0 + wi)) * DI + d0] = r;
  }
}

// ---------------------------------------------------------------------------
// Kernel 3: x_dbl projections. Register-tiled GEMM, 64l x 80s tile, 4x5 reg.
// ---------------------------------------------------------------------------
__global__ __launch_bounds__(256) void k_proj(const float* __restrict__ xf,
                                              const float* __restrict__ xpw,
                                              float* __restrict__ proj) {
  __shared__ float smem[5376];     // As[32][68] | Ws[32][84]; reused as res[64][84]
  float* As = smem;
  float* Ws = smem + 32 * 68;
  const int tid = threadIdx.x;
  const int row0 = blockIdx.x * 64;
  const int b = row0 >> 13;
  const int l0 = row0 & (LL - 1);
  const int tx = tid & 15;
  const int ty = tid >> 4;
  float acc[4][5] = {};

  for (int kc = 0; kc < 6; ++kc) {
    const int d0 = kc * 32;
    __syncthreads();
    for (int v = tid; v < 512; v += 256) {
      const int l = v >> 3, dk4 = v & 7;
      const float4 xv =
          *(const float4*)&xf[((size_t)b * LL + l0 + l) * DI + d0 + dk4 * 4];
      As[(dk4 * 4 + 0) * 68 + l] = xv.x;
      As[(dk4 * 4 + 1) * 68 + l] = xv.y;
      As[(dk4 * 4 + 2) * 68 + l] = xv.z;
      As[(dk4 * 4 + 3) * 68 + l] = xv.w;
    }
    for (int v = tid; v < 640; v += 256) {
      const int s = v >> 3, dk4 = v & 7;
      const int k = s / 40, off = s % 40;
      float4 wv = make_float4(0.f, 0.f, 0.f, 0.f);
      if (off < 6 || off >= 8) {
        const int c = off < 6 ? off : off - 2;
        wv = *(const float4*)&xpw[(size_t)(k * 38 + c) * DI + d0 + dk4 * 4];
      }
      Ws[(dk4 * 4 + 0) * 84 + s] = wv.x;
      Ws[(dk4 * 4 + 1) * 84 + s] = wv.y;
      Ws[(dk4 * 4 + 2) * 84 + s] = wv.z;
      Ws[(dk4 * 4 + 3) * 84 + s] = wv.w;
    }
    __syncthreads();
    for (int dk = 0; dk < 32; ++dk) {
      const float4 a4 = *(const float4*)&As[dk * 68 + ty * 4];
      float w[5];
#pragma unroll
      for (int j = 0; j < 5; ++j) w[j] = Ws[dk * 84 + tx * 5 + j];
      const float av[4] = {a4.x, a4.y, a4.z, a4.w};
#pragma unroll
      for (int i = 0; i < 4; ++i)
#pragma unroll
        for (int j = 0; j < 5; ++j)
          acc[i][j] = fmaf(av[i], w[j], acc[i][j]);
    }
  }

  __syncthreads();
  float* res = smem;  // [64][84]
#pragma unroll
  for (int i = 0; i < 4; ++i)
#pragma unroll
    for (int j = 0; j < 5; ++j)
      res[(ty * 4 + i) * 84 + tx * 5 + j] = acc[i][j];
  __syncthreads();
#pragma unroll
  for (int k = 0; k < 2; ++k) {
    float* dst = proj + ((size_t)(b * Kk + k) * LL + l0) * PROJ_C;
    for (int v = tid; v < 640; v += 256) {
      const int l = v / 10, q = v % 10;
      *(float4*)&dst[l * PROJ_C + q * 4] =
          *(const float4*)&res[l * 84 + k * 40 + q * 4];
    }
  }
}

// ---------------------------------------------------------------------------
// Kernel 4: delta[b,k,l,d] = softplus(dts_r . dtw + bias), float4 over d.
// ---------------------------------------------------------------------------
__global__ __launch_bounds__(256) void k_delta(const float* __restrict__ proj,
                                               const float* __restrict__ dtw_,
                                               const float* __restrict__ dtb_,
                                               float* __restrict__ delta) {
  int gid = blockIdx.x * 256 + threadIdx.x;
  int d4 = gid % 48;
  int rem = gid / 48;
  int l = rem % LL;
  int bk = rem / LL;
  int k = bk & 1;
  const float* pr = proj + (size_t)(bk * LL + l) * PROJ_C;
  float p[6];
#pragma unroll
  for (int r = 0; r < 6; ++r) p[r] = pr[r];
  float4 res;
#pragma unroll
  for (int j = 0; j < 4; ++j) {
    int kd = k * DI + d4 * 4 + j;
    const float* w6 = dtw_ + (size_t)kd * 6;
    float draw = dtb_[kd];
#pragma unroll
    for (int r = 0; r < 6; ++r) draw = fmaf(p[r], w6[r], draw);
    ((float*)&res)[j] = softplusf_(draw);
  }
  *(float4*)&delta[(size_t)(bk * LL + l) * DI + d4 * 4] = res;
}

// ---------------------------------------------------------------------------
// Scan kernels, templated on pass and direction (KD). 4 lanes x 4 states
// per d. Explicit 1-step software pipeline: next step's loads issue before
// the current step's exp/FMA chain. (One-element overread on the final
// iteration stays inside d_ws — values discarded.)
// PASS 1: h from 0 -> hend, P=exp(A*sum d). PASS 3: h from hinit, emit
// y[b,d,l] (KD=0 stores, KD=1 accumulates; stream-ordered, race-free).
// ---------------------------------------------------------------------------
template <int PASS, int KD>
__global__ __launch_bounds__(256) void k_scan(
    const float* __restrict__ delta, const float* __restrict__ proj,
    const float* __restrict__ xf, const float* __restrict__ Alog,
    const float* __restrict__ Dsv, const float* __restrict__ hinit,
    float* __restrict__ hend, float* __restrict__ Pst,
    float* __restrict__ yout) {
  const int tid = threadIdx.x;
  const int sub = tid & 3, gi = tid >> 2;
  int rest = blockIdx.x;
  const int dt3 = rest % 3;  rest /= 3;
  const int g = rest % G;
  const int b = rest / G;
  const int d = dt3 * 64 + gi;
  const int kd = KD * DI + d;
  const int bk = b * Kk + KD;

  float A[4];
#pragma unroll
  for (int i = 0; i < 4; ++i) A[i] = -__expf(Alog[kd * 16 + sub * 4 + i]);

  const size_t gidx = (((size_t)(bk * G + g)) * DI + d) * Nn + sub * 4;
  float h[4];
  if (PASS == 1) {
    h[0] = h[1] = h[2] = h[3] = 0.f;
  } else {
    float4 h4 = *(const float4*)&hinit[gidx];
    h[0] = h4.x; h[1] = h4.y; h[2] = h4.z; h[3] = h4.w;
  }
  const float Dv = (PASS == 3) ? Dsv[kd] : 0.f;

  constexpr int STP = KD ? -1 : 1;
  constexpr int DSTP = STP * DI, PSTP = STP * PROJ_C;
  const int l_start = KD ? (LL - 1 - g * CH) : (g * CH);
  const float* dp = delta + ((size_t)bk * LL + l_start) * DI + d;
  const float* up = xf + ((size_t)b * LL + l_start) * DI + d;
  const float* pp = proj + ((size_t)bk * LL + l_start) * PROJ_C + 8 + sub * 4;
  const size_t ybase = ((size_t)b * DI + d) * LL;

  // pipeline primer
  float dlt_c = *dp;
  float u_c = *up;
  float4 B_c = *(const float4*)pp;
  float4 C_c;
  if (PASS == 3) C_c = *(const float4*)(pp + 16);

  float dsum = 0.f, ybuf = 0.f;
#pragma unroll 4
  for (int t = 0; t < CH; ++t) {
    dp += DSTP; up += DSTP; pp += PSTP;
    const float dlt_n = *dp;   // prefetch (overreads 1 row on last iter, ok)
    const float u_n = *up;
    const float4 B_n = *(const float4*)pp;
    float4 C_n;
    if (PASS == 3) C_n = *(const float4*)(pp + 16);

    const float du = dlt_c * u_c;
    if (PASS == 1) {
#pragma unroll
      for (int i = 0; i < 4; ++i)
        h[i] = fmaf(__expf(dlt_c * A[i]), h[i], du * ((const float*)&B_c)[i]);
      dsum += dlt_c;
    } else {
      float yp = 0.f;
#pragma unroll
      for (int i = 0; i < 4; ++i) {
        h[i] = fmaf(__expf(dlt_c * A[i]), h[i], du * ((const float*)&B_c)[i]);
        yp = fmaf(h[i], ((const float*)&C_c)[i], yp);
      }
      yp += __shfl_xor(yp, 1, 64);
      yp += __shfl_xor(yp, 2, 64);
      const float yt = fmaf(u_c, Dv, yp);
      ybuf = ((t & 3) == sub) ? yt : ybuf;
      if ((t & 3) == 3) {
        const int tau = g * CH + (t & ~3) + sub;
        const int lp = KD ? (LL - 1 - tau) : tau;
        if (KD == 0)
          yout[ybase + lp] = ybuf;
        else
          yout[ybase + lp] += ybuf;  // k=0 pass already wrote; stream-ordered
      }
    }
    dlt_c = dlt_n; u_c = u_n; B_c = B_n;
    if (PASS == 3) C_c = C_n;
  }
  if (PASS == 1) {
    float4 hv = make_float4(h[0], h[1], h[2], h[3]);
    float4 pv = make_float4(__expf(A[0] * dsum), __expf(A[1] * dsum),
                            __expf(A[2] * dsum), __expf(A[3] * dsum));
    *(float4*)&hend[gidx] = hv;
    *(float4*)&Pst[gidx] = pv;
  }
}

// Pass 2: combine chunk summaries sequentially per (b,k,d,n). Unrolled so
// the G loads batch ahead of the dependent fma chain.
__global__ __launch_bounds__(256) void k_scan2(const float* __restrict__ hend,
                                               const float* __restrict__ Pst,
                                               float* __restrict__ hini) {
  int idx = blockIdx.x * 256 + threadIdx.x;
  int n = idx & 15;
  int rem = idx >> 4;
  int d = rem % DI;
  int bk = rem / DI;
  float carry = 0.f;
#pragma unroll 8
  for (int g = 0; g < G; ++g) {
    size_t a = (((size_t)(bk * G + g)) * DI + d) * Nn + n;
    float hv = hend[a], pv = Pst[a];
    hini[a] = carry;
    carry = fmaf(pv, carry, hv);
  }
}

// ---------------------------------------------------------------------------
// Kernel 7: out[l,c] = sum_d (y[b,d,l]*silu(z[b,l,d])) * Wout[c,d]
// Register-tiled GEMM: 128l x 96c block tile, K chunked by 32, 4x12 reg tile.
// ---------------------------------------------------------------------------
__global__ __launch_bounds__(256) void k_out(const float* __restrict__ y,
                                             const float* __restrict__ zbuf,
                                             const float* __restrict__ Wout,
                                             float* __restrict__ out) {
  __shared__ float As[32][132];
  __shared__ float Ws[32][100];
  const int tid = threadIdx.x;
  const int row0 = blockIdx.x * 128;
  const int b = row0 >> 13;
  const int l0 = row0 & (LL - 1);
  const int tx = tid & 7;
  const int ty = tid >> 3;
  float acc[4][12] = {};

  for (int kc = 0; kc < 6; ++kc) {
    const int d0 = kc * 32;
    __syncthreads();
    for (int v = tid; v < 1024; v += 256) {
      const int l = v >> 3, dk4 = v & 7;
      const float4 zv = *(const float4*)&zbuf[((size_t)b * LL + l0 + l) * DI +
                                              d0 + dk4 * 4];
      As[dk4 * 4 + 0][l] = zv.x * sigmoidf_(zv.x);
      As[dk4 * 4 + 1][l] = zv.y * sigmoidf_(zv.y);
      As[dk4 * 4 + 2][l] = zv.z * sigmoidf_(zv.z);
      As[dk4 * 4 + 3][l] = zv.w * sigmoidf_(zv.w);
    }
    for (int v = tid; v < 768; v += 256) {
      const int c = v >> 3, dk4 = v & 7;
      const float4 wv = *(const float4*)&Wout[(size_t)c * DI + d0 + dk4 * 4];
      Ws[dk4 * 4 + 0][c] = wv.x;
      Ws[dk4 * 4 + 1][c] = wv.y;
      Ws[dk4 * 4 + 2][c] = wv.z;
      Ws[dk4 * 4 + 3][c] = wv.w;
    }
    __syncthreads();
    for (int v = tid; v < 1024; v += 256) {
      const int dk = v >> 5, l4 = v & 31;
      const float4 yv =
          *(const float4*)&y[((size_t)b * DI + d0 + dk) * LL + l0 + l4 * 4];
      As[dk][l4 * 4 + 0] *= yv.x;
      As[dk][l4 * 4 + 1] *= yv.y;
      As[dk][l4 * 4 + 2] *= yv.z;
      As[dk][l4 * 4 + 3] *= yv.w;
    }
    __syncthreads();
    for (int dk = 0; dk < 32; ++dk) {
      const float4 a4 = *(const float4*)&As[dk][ty * 4];
      const float4 w0 = *(const float4*)&Ws[dk][tx * 12];
      const float4 w1 = *(const float4*)&Ws[dk][tx * 12 + 4];
      const float4 w2 = *(const float4*)&Ws[dk][tx * 12 + 8];
      const float av[4] = {a4.x, a4.y, a4.z, a4.w};
      const float wv[12] = {w0.x, w0.y, w0.z, w0.w, w1.x, w1.y,
                            w1.z, w1.w, w2.x, w2.y, w2.z, w2.w};
#pragma unroll
      for (int i = 0; i < 4; ++i)
#pragma unroll
        for (int j = 0; j < 12; ++j)
          acc[i][j] = fmaf(av[i], wv[j], acc[i][j]);
    }
  }

#pragma unroll
  for (int i = 0; i < 4; ++i) {
    float* op = out + ((size_t)b * LL + l0 + ty * 4 + i) * 96 + tx * 12;
    *(float4*)(op + 0) = make_float4(acc[i][0], acc[i][1], acc[i][2], acc[i][3]);
    *(float4*)(op + 4) = make_float4(acc[i][4], acc[i][5], acc[i][6], acc[i][7]);
    *(float4*)(op + 8) = make_float4(acc[i][8], acc[i][9], acc[i][10], acc[i][11]);
  }
}

// ---------------------------------------------------------------------------
extern "C" void kernel_launch(void* const* d_in, const int* in_sizes, int n_in,
                              void* d_out, int out_size, void* d_ws,
                              size_t ws_size, hipStream_t stream) {
  const float* x    = (const float*)d_in[0];
  const float* Win  = (const float*)d_in[1];
  const float* cw   = (const float*)d_in[2];
  const float* cb   = (const float*)d_in[3];
  const float* xpw  = (const float*)d_in[4];
  const float* dtw  = (const float*)d_in[5];
  const float* dtb  = (const float*)d_in[6];
  const float* Alog = (const float*)d_in[7];
  const float* Dsv  = (const float*)d_in[8];
  const float* Wout = (const float*)d_in[9];
  float* out = (float*)d_out;

  float* ws = (float*)d_ws;
  size_t o = 0;
  float* zbuf  = ws + o;  o += (size_t)ROWS * DI;                 // 25.2 MB
  float* xf    = ws + o;  o += (size_t)ROWS * DI;                 // 25.2 MB
  float* proj  = ws + o;  o += (size_t)Bb * Kk * LL * PROJ_C;     // 10.5 MB
  float* delta = ws + o;  o += (size_t)Bb * Kk * LL * DI;         // 50.3 MB
  const size_t hsz = (size_t)Bb * Kk * G * DI * Nn;               // G=128: 12.6 MB ea
  float* hend = ws + o;  o += hsz;
  float* Pst  = ws + o;  o += hsz;
  float* hini = ws + o;  o += hsz;
  float* y    = ws + o;  o += (size_t)Bb * DI * LL;               // 25.2 MB
  float* xc   = y;  // alias: xc dead after conv, before y is written

  k_xz<<<dim3(ROWS / 64, 6), 256, 0, stream>>>(x, Win, xc, zbuf);
  k_conv<<<dim3((Bb * Hh * 64 * 48) / 256), 256, 0, stream>>>(xc, cw, cb, xf);
  k_proj<<<dim3(ROWS / 64), 256, 0, stream>>>(xf, xpw, proj);
  k_delta<<<dim3((Bb * Kk * LL * 48) / 256), 256, 0, stream>>>(proj, dtw, dtb,
                                                               delta);
  k_scan<1, 0><<<dim3(Bb * G * 3), 256, 0, stream>>>(
      delta, proj, xf, Alog, Dsv, nullptr, hend, Pst, nullptr);
  k_scan<1, 1><<<dim3(Bb * G * 3), 256, 0, stream>>>(
      delta, proj, xf, Alog, Dsv, nullptr, hend, Pst, nullptr);
  k_scan2<<<dim3((Bb * Kk * DI * Nn) / 256), 256, 0, stream>>>(hend, Pst,
                                                               hini);
  k_scan<3, 0><<<dim3(Bb * G * 3), 256, 0, stream>>>(
      delta, proj, xf, Alog, Dsv, hini, nullptr, nullptr, y);
  k_scan<3, 1><<<dim3(Bb * G * 3), 256, 0, stream>>>(
      delta, proj, xf, Alog, Dsv, hini, nullptr, nullptr, y);
  k_out<<<dim3(ROWS / 128), 256, 0, stream>>>(y, zbuf, Wout, out);
}

// Round 7
// 350.887 us; speedup vs baseline: 1.2722x; 1.0150x over previous
//
#include <hip/hip_runtime.h>

// Problem constants
constexpr int Bb = 4, Hh = 32, Wd = 256, Cc = 96;
constexpr int DI = 192, Nn = 16, Rr = 6, Kk = 2;
constexpr int LL = Hh * Wd;          // 8192
constexpr int ROWS = Bb * LL;        // 32768
constexpr int PROJ_C = 40;           // [0..5]=dts, pad, [8..23]=B, [24..39]=C
constexpr int G = 128;               // scan chunks
constexpr int CH = LL / G;           // 64 steps per chunk

static __device__ __forceinline__ float sigmoidf_(float v) {
  return 1.f / (1.f + __expf(-v));
}
static __device__ __forceinline__ float softplusf_(float v) {
  return v > 20.f ? v : __logf(1.f + __expf(v));
}

// ---------------------------------------------------------------------------
// Kernel 1: xz = x @ W_in^T  (32768 x 384, K=96).
// 64row x 128col block tile, one-shot K staging, 4x8 register tile.
// LDS layout transposed [k][m] so fragment reads are 2-way max on banks
// (bank = (4(k+tx)+j)%32 spreads over all 32). FMA:LDS-float ratio 32:12.
// ---------------------------------------------------------------------------
__global__ __launch_bounds__(256) void k_xz(const float* __restrict__ x,
                                            const float* __restrict__ Win,
                                            float* __restrict__ xc,
                                            float* __restrict__ zbuf) {
  __shared__ float As[96 * 68];    // [k][row], stride 68 (272B, 16B-aligned)
  __shared__ float Bs[96 * 132];   // [k][col], stride 132 (528B, 16B-aligned)
  const int tid = threadIdx.x;
  const int row0 = blockIdx.x * 64;
  const int col0 = blockIdx.y * 128;

  // stage A: 64 rows x 96 k. Coalesced: lanes sweep k within a row.
  for (int v = tid; v < 64 * 24; v += 256) {
    const int kq = v % 24, r = v / 24;
    const float4 xv = *(const float4*)&x[(size_t)(row0 + r) * 96 + kq * 4];
    As[(kq * 4 + 0) * 68 + r] = xv.x;
    As[(kq * 4 + 1) * 68 + r] = xv.y;
    As[(kq * 4 + 2) * 68 + r] = xv.z;
    As[(kq * 4 + 3) * 68 + r] = xv.w;
  }
  // stage B: 128 cols x 96 k.
  for (int v = tid; v < 128 * 24; v += 256) {
    const int kq = v % 24, c = v / 24;
    const float4 wv = *(const float4*)&Win[(size_t)(col0 + c) * 96 + kq * 4];
    Bs[(kq * 4 + 0) * 132 + c] = wv.x;
    Bs[(kq * 4 + 1) * 132 + c] = wv.y;
    Bs[(kq * 4 + 2) * 132 + c] = wv.z;
    Bs[(kq * 4 + 3) * 132 + c] = wv.w;
  }
  __syncthreads();

  const int tx = tid & 15, ty = tid >> 4;   // cols: tx*4, tx*4+64; rows: ty*4+i
  float acc[4][8] = {};
#pragma unroll 4
  for (int k = 0; k < 96; ++k) {
    const float4 a4 = *(const float4*)&As[k * 68 + ty * 4];
    const float4 b0 = *(const float4*)&Bs[k * 132 + tx * 4];
    const float4 b1 = *(const float4*)&Bs[k * 132 + tx * 4 + 64];
    const float av[4] = {a4.x, a4.y, a4.z, a4.w};
    const float bv[8] = {b0.x, b0.y, b0.z, b0.w, b1.x, b1.y, b1.z, b1.w};
#pragma unroll
    for (int i = 0; i < 4; ++i)
#pragma unroll
      for (int j = 0; j < 8; ++j)
        acc[i][j] = fmaf(av[i], bv[j], acc[i][j]);
  }

#pragma unroll
  for (int i = 0; i < 4; ++i) {
    const int R = row0 + ty * 4 + i;
    const int g0 = col0 + tx * 4;
    const float4 v0 = make_float4(acc[i][0], acc[i][1], acc[i][2], acc[i][3]);
    const float4 v1 = make_float4(acc[i][4], acc[i][5], acc[i][6], acc[i][7]);
    if (g0 < DI)
      *(float4*)&xc[(size_t)R * DI + g0] = v0;
    else
      *(float4*)&zbuf[(size_t)R * DI + (g0 - DI)] = v0;
    const int g1 = g0 + 64;
    if (g1 < DI)
      *(float4*)&xc[(size_t)R * DI + g1] = v1;
    else
      *(float4*)&zbuf[(size_t)R * DI + (g1 - DI)] = v1;
  }
}

// ---------------------------------------------------------------------------
// Kernel 2: depthwise 3x3 conv + bias + SiLU. Branch-free, 18 unconditional
// masked halo loads, weights transposed in LDS.
// ---------------------------------------------------------------------------
__global__ __launch_bounds__(256) void k_conv(const float* __restrict__ xc,
                                              const float* __restrict__ cw,
                                              const float* __restrict__ cbias,
                                              float* __restrict__ xf) {
  __shared__ float wl[9 * DI];   // [tap][d]
  __shared__ float bl[DI];
  const int tid = threadIdx.x;
  for (int v = tid; v < 9 * DI; v += 256) {
    int dd = v / 9, t = v % 9;
    wl[t * DI + dd] = cw[v];
  }
  if (tid < DI) bl[tid] = cbias[tid];
  __syncthreads();

  int gid = blockIdx.x * 256 + tid;  // (b, h, w4, d4), d4 fast
  int d4 = gid % 48;
  int rem = gid / 48;
  int w4 = rem % 64;
  int bh = rem / 64;
  int h = bh % Hh, b = bh / Hh;
  const int d0 = d4 * 4, w0 = w4 * 4;

  float4 c[3][6];
#pragma unroll
  for (int dr = 0; dr < 3; ++dr) {
    const int h2 = h + dr - 1;
    const bool hv = (unsigned)h2 < (unsigned)Hh;
    const int hc = hv ? h2 : h;
    const float* rp = xc + ((size_t)(b * LL + (hc << 8))) * DI + d0;
#pragma unroll
    for (int j = 0; j < 6; ++j) {
      const int wc = w0 - 1 + j;
      const bool wv = (unsigned)wc < (unsigned)Wd;
      const int wcc = wv ? wc : w0;
      float4 v = *(const float4*)&rp[(size_t)wcc * DI];
      const float m = (hv && wv) ? 1.f : 0.f;
      c[dr][j] = make_float4(v.x * m, v.y * m, v.z * m, v.w * m);
    }
  }

  float4 wv9[9];
#pragma unroll
  for (int t = 0; t < 9; ++t) wv9[t] = *(const float4*)&wl[t * DI + d0];
  const float4 bias4 = *(const float4*)&bl[d0];

#pragma unroll
  for (int wi = 0; wi < 4; ++wi) {
    float4 a = bias4;
#pragma unroll
    for (int dr = 0; dr < 3; ++dr)
#pragma unroll
      for (int dc = 0; dc < 3; ++dc) {
        const float4 vv = c[dr][wi + dc];
        const float4 ww = wv9[dr * 3 + dc];
        a.x = fmaf(vv.x, ww.x, a.x);
        a.y = fmaf(vv.y, ww.y, a.y);
        a.z = fmaf(vv.z, ww.z, a.z);
        a.w = fmaf(vv.w, ww.w, a.w);
      }
    float4 r;
    r.x = a.x * sigmoidf_(a.x);
    r.y = a.y * sigmoidf_(a.y);
    r.z = a.z * sigmoidf_(a.z);
    r.w = a.w * sigmoidf_(a.w);
    *(float4*)&xf[((size_t)(b * LL + (h << 8) + w0 + wi)) * DI + d0] = r;
  }
}

// ---------------------------------------------------------------------------
// Kernel 3: x_dbl projections. Register-tiled GEMM, 64l x 80s tile, 4x5 reg.
// ---------------------------------------------------------------------------
__global__ __launch_bounds__(256) void k_proj(const float* __restrict__ xf,
                                              const float* __restrict__ xpw,
                                              float* __restrict__ proj) {
  __shared__ float smem[5376];     // As[32][68] | Ws[32][84]; reused as res[64][84]
  float* As = smem;
  float* Ws = smem + 32 * 68;
  const int tid = threadIdx.x;
  const int row0 = blockIdx.x * 64;
  const int b = row0 >> 13;
  const int l0 = row0 & (LL - 1);
  const int tx = tid & 15;
  const int ty = tid >> 4;
  float acc[4][5] = {};

  for (int kc = 0; kc < 6; ++kc) {
    const int d0 = kc * 32;
    __syncthreads();
    for (int v = tid; v < 512; v += 256) {
      const int l = v >> 3, dk4 = v & 7;
      const float4 xv =
          *(const float4*)&xf[((size_t)b * LL + l0 + l) * DI + d0 + dk4 * 4];
      As[(dk4 * 4 + 0) * 68 + l] = xv.x;
      As[(dk4 * 4 + 1) * 68 + l] = xv.y;
      As[(dk4 * 4 + 2) * 68 + l] = xv.z;
      As[(dk4 * 4 + 3) * 68 + l] = xv.w;
    }
    for (int v = tid; v < 640; v += 256) {
      const int s = v >> 3, dk4 = v & 7;
      const int k = s / 40, off = s % 40;
      float4 wv = make_float4(0.f, 0.f, 0.f, 0.f);
      if (off < 6 || off >= 8) {
        const int c = off < 6 ? off : off - 2;
        wv = *(const float4*)&xpw[(size_t)(k * 38 + c) * DI + d0 + dk4 * 4];
      }
      Ws[(dk4 * 4 + 0) * 84 + s] = wv.x;
      Ws[(dk4 * 4 + 1) * 84 + s] = wv.y;
      Ws[(dk4 * 4 + 2) * 84 + s] = wv.z;
      Ws[(dk4 * 4 + 3) * 84 + s] = wv.w;
    }
    __syncthreads();
    for (int dk = 0; dk < 32; ++dk) {
      const float4 a4 = *(const float4*)&As[dk * 68 + ty * 4];
      float w[5];
#pragma unroll
      for (int j = 0; j < 5; ++j) w[j] = Ws[dk * 84 + tx * 5 + j];
      const float av[4] = {a4.x, a4.y, a4.z, a4.w};
#pragma unroll
      for (int i = 0; i < 4; ++i)
#pragma unroll
        for (int j = 0; j < 5; ++j)
          acc[i][j] = fmaf(av[i], w[j], acc[i][j]);
    }
  }

  __syncthreads();
  float* res = smem;  // [64][84]
#pragma unroll
  for (int i = 0; i < 4; ++i)
#pragma unroll
    for (int j = 0; j < 5; ++j)
      res[(ty * 4 + i) * 84 + tx * 5 + j] = acc[i][j];
  __syncthreads();
#pragma unroll
  for (int k = 0; k < 2; ++k) {
    float* dst = proj + ((size_t)(b * Kk + k) * LL + l0) * PROJ_C;
    for (int v = tid; v < 640; v += 256) {
      const int l = v / 10, q = v % 10;
      *(float4*)&dst[l * PROJ_C + q * 4] =
          *(const float4*)&res[l * 84 + k * 40 + q * 4];
    }
  }
}

// ---------------------------------------------------------------------------
// Kernel 4: delta[b,k,l,d] = softplus(dts_r . dtw + bias), float4 over d.
// ---------------------------------------------------------------------------
__global__ __launch_bounds__(256) void k_delta(const float* __restrict__ proj,
                                               const float* __restrict__ dtw_,
                                               const float* __restrict__ dtb_,
                                               float* __restrict__ delta) {
  int gid = blockIdx.x * 256 + threadIdx.x;
  int d4 = gid % 48;
  int rem = gid / 48;
  int l = rem % LL;
  int bk = rem / LL;
  int k = bk & 1;
  const float* pr = proj + (size_t)(bk * LL + l) * PROJ_C;
  float p[6];
#pragma unroll
  for (int r = 0; r < 6; ++r) p[r] = pr[r];
  float4 res;
#pragma unroll
  for (int j = 0; j < 4; ++j) {
    int kd = k * DI + d4 * 4 + j;
    const float* w6 = dtw_ + (size_t)kd * 6;
    float draw = dtb_[kd];
#pragma unroll
    for (int r = 0; r < 6; ++r) draw = fmaf(p[r], w6[r], draw);
    ((float*)&res)[j] = softplusf_(draw);
  }
  *(float4*)&delta[(size_t)(bk * LL + l) * DI + d4 * 4] = res;
}

// ---------------------------------------------------------------------------
// Scan kernels, templated on pass and direction (KD). 4 lanes x 4 states
// per d, 1-step software pipeline.
// ---------------------------------------------------------------------------
template <int PASS, int KD>
__global__ __launch_bounds__(256) void k_scan(
    const float* __restrict__ delta, const float* __restrict__ proj,
    const float* __restrict__ xf, const float* __restrict__ Alog,
    const float* __restrict__ Dsv, const float* __restrict__ hinit,
    float* __restrict__ hend, float* __restrict__ Pst,
    float* __restrict__ yout) {
  const int tid = threadIdx.x;
  const int sub = tid & 3, gi = tid >> 2;
  int rest = blockIdx.x;
  const int dt3 = rest % 3;  rest /= 3;
  const int g = rest % G;
  const int b = rest / G;
  const int d = dt3 * 64 + gi;
  const int kd = KD * DI + d;
  const int bk = b * Kk + KD;

  float A[4];
#pragma unroll
  for (int i = 0; i < 4; ++i) A[i] = -__expf(Alog[kd * 16 + sub * 4 + i]);

  const size_t gidx = (((size_t)(bk * G + g)) * DI + d) * Nn + sub * 4;
  float h[4];
  if (PASS == 1) {
    h[0] = h[1] = h[2] = h[3] = 0.f;
  } else {
    float4 h4 = *(const float4*)&hinit[gidx];
    h[0] = h4.x; h[1] = h4.y; h[2] = h4.z; h[3] = h4.w;
  }
  const float Dv = (PASS == 3) ? Dsv[kd] : 0.f;

  constexpr int STP = KD ? -1 : 1;
  constexpr int DSTP = STP * DI, PSTP = STP * PROJ_C;
  const int l_start = KD ? (LL - 1 - g * CH) : (g * CH);
  const float* dp = delta + ((size_t)bk * LL + l_start) * DI + d;
  const float* up = xf + ((size_t)b * LL + l_start) * DI + d;
  const float* pp = proj + ((size_t)bk * LL + l_start) * PROJ_C + 8 + sub * 4;
  const size_t ybase = ((size_t)b * DI + d) * LL;

  float dlt_c = *dp;
  float u_c = *up;
  float4 B_c = *(const float4*)pp;
  float4 C_c;
  if (PASS == 3) C_c = *(const float4*)(pp + 16);

  float dsum = 0.f, ybuf = 0.f;
#pragma unroll 4
  for (int t = 0; t < CH; ++t) {
    dp += DSTP; up += DSTP; pp += PSTP;
    const float dlt_n = *dp;   // prefetch (overreads 1 row on last iter, ok)
    const float u_n = *up;
    const float4 B_n = *(const float4*)pp;
    float4 C_n;
    if (PASS == 3) C_n = *(const float4*)(pp + 16);

    const float du = dlt_c * u_c;
    if (PASS == 1) {
#pragma unroll
      for (int i = 0; i < 4; ++i)
        h[i] = fmaf(__expf(dlt_c * A[i]), h[i], du * ((const float*)&B_c)[i]);
      dsum += dlt_c;
    } else {
      float yp = 0.f;
#pragma unroll
      for (int i = 0; i < 4; ++i) {
        h[i] = fmaf(__expf(dlt_c * A[i]), h[i], du * ((const float*)&B_c)[i]);
        yp = fmaf(h[i], ((const float*)&C_c)[i], yp);
      }
      yp += __shfl_xor(yp, 1, 64);
      yp += __shfl_xor(yp, 2, 64);
      const float yt = fmaf(u_c, Dv, yp);
      ybuf = ((t & 3) == sub) ? yt : ybuf;
      if ((t & 3) == 3) {
        const int tau = g * CH + (t & ~3) + sub;
        const int lp = KD ? (LL - 1 - tau) : tau;
        if (KD == 0)
          yout[ybase + lp] = ybuf;
        else
          yout[ybase + lp] += ybuf;  // k=0 pass already wrote; stream-ordered
      }
    }
    dlt_c = dlt_n; u_c = u_n; B_c = B_n;
    if (PASS == 3) C_c = C_n;
  }
  if (PASS == 1) {
    float4 hv = make_float4(h[0], h[1], h[2], h[3]);
    float4 pv = make_float4(__expf(A[0] * dsum), __expf(A[1] * dsum),
                            __expf(A[2] * dsum), __expf(A[3] * dsum));
    *(float4*)&hend[gidx] = hv;
    *(float4*)&Pst[gidx] = pv;
  }
}

// Pass 2: combine chunk summaries sequentially per (b,k,d,n).
__global__ __launch_bounds__(256) void k_scan2(const float* __restrict__ hend,
                                               const float* __restrict__ Pst,
                                               float* __restrict__ hini) {
  int idx = blockIdx.x * 256 + threadIdx.x;
  int n = idx & 15;
  int rem = idx >> 4;
  int d = rem % DI;
  int bk = rem / DI;
  float carry = 0.f;
#pragma unroll 8
  for (int g = 0; g < G; ++g) {
    size_t a = (((size_t)(bk * G + g)) * DI + d) * Nn + n;
    float hv = hend[a], pv = Pst[a];
    hini[a] = carry;
    carry = fmaf(pv, carry, hv);
  }
}

// ---------------------------------------------------------------------------
// Kernel 7: out[l,c] = sum_d (y[b,d,l]*silu(z[b,l,d])) * Wout[c,d]
// Register-tiled GEMM: 128l x 96c block tile, K chunked by 32, 4x12 reg tile.
// ---------------------------------------------------------------------------
__global__ __launch_bounds__(256) void k_out(const float* __restrict__ y,
                                             const float* __restrict__ zbuf,
                                             const float* __restrict__ Wout,
                                             float* __restrict__ out) {
  __shared__ float As[32][132];
  __shared__ float Ws[32][100];
  const int tid = threadIdx.x;
  const int row0 = blockIdx.x * 128;
  const int b = row0 >> 13;
  const int l0 = row0 & (LL - 1);
  const int tx = tid & 7;
  const int ty = tid >> 3;
  float acc[4][12] = {};

  for (int kc = 0; kc < 6; ++kc) {
    const int d0 = kc * 32;
    __syncthreads();
    for (int v = tid; v < 1024; v += 256) {
      const int l = v >> 3, dk4 = v & 7;
      const float4 zv = *(const float4*)&zbuf[((size_t)b * LL + l0 + l) * DI +
                                              d0 + dk4 * 4];
      As[dk4 * 4 + 0][l] = zv.x * sigmoidf_(zv.x);
      As[dk4 * 4 + 1][l] = zv.y * sigmoidf_(zv.y);
      As[dk4 * 4 + 2][l] = zv.z * sigmoidf_(zv.z);
      As[dk4 * 4 + 3][l] = zv.w * sigmoidf_(zv.w);
    }
    for (int v = tid; v < 768; v += 256) {
      const int c = v >> 3, dk4 = v & 7;
      const float4 wv = *(const float4*)&Wout[(size_t)c * DI + d0 + dk4 * 4];
      Ws[dk4 * 4 + 0][c] = wv.x;
      Ws[dk4 * 4 + 1][c] = wv.y;
      Ws[dk4 * 4 + 2][c] = wv.z;
      Ws[dk4 * 4 + 3][c] = wv.w;
    }
    __syncthreads();
    for (int v = tid; v < 1024; v += 256) {
      const int dk = v >> 5, l4 = v & 31;
      const float4 yv =
          *(const float4*)&y[((size_t)b * DI + d0 + dk) * LL + l0 + l4 * 4];
      As[dk][l4 * 4 + 0] *= yv.x;
      As[dk][l4 * 4 + 1] *= yv.y;
      As[dk][l4 * 4 + 2] *= yv.z;
      As[dk][l4 * 4 + 3] *= yv.w;
    }
    __syncthreads();
    for (int dk = 0; dk < 32; ++dk) {
      const float4 a4 = *(const float4*)&As[dk][ty * 4];
      const float4 w0 = *(const float4*)&Ws[dk][tx * 12];
      const float4 w1 = *(const float4*)&Ws[dk][tx * 12 + 4];
      const float4 w2 = *(const float4*)&Ws[dk][tx * 12 + 8];
      const float av[4] = {a4.x, a4.y, a4.z, a4.w};
      const float wv[12] = {w0.x, w0.y, w0.z, w0.w, w1.x, w1.y,
                            w1.z, w1.w, w2.x, w2.y, w2.z, w2.w};
#pragma unroll
      for (int i = 0; i < 4; ++i)
#pragma unroll
        for (int j = 0; j < 12; ++j)
          acc[i][j] = fmaf(av[i], wv[j], acc[i][j]);
    }
  }

#pragma unroll
  for (int i = 0; i < 4; ++i) {
    float* op = out + ((size_t)b * LL + l0 + ty * 4 + i) * 96 + tx * 12;
    *(float4*)(op + 0) = make_float4(acc[i][0], acc[i][1], acc[i][2], acc[i][3]);
    *(float4*)(op + 4) = make_float4(acc[i][4], acc[i][5], acc[i][6], acc[i][7]);
    *(float4*)(op + 8) = make_float4(acc[i][8], acc[i][9], acc[i][10], acc[i][11]);
  }
}

// ---------------------------------------------------------------------------
extern "C" void kernel_launch(void* const* d_in, const int* in_sizes, int n_in,
                              void* d_out, int out_size, void* d_ws,
                              size_t ws_size, hipStream_t stream) {
  const float* x    = (const float*)d_in[0];
  const float* Win  = (const float*)d_in[1];
  const float* cw   = (const float*)d_in[2];
  const float* cb   = (const float*)d_in[3];
  const float* xpw  = (const float*)d_in[4];
  const float* dtw  = (const float*)d_in[5];
  const float* dtb  = (const float*)d_in[6];
  const float* Alog = (const float*)d_in[7];
  const float* Dsv  = (const float*)d_in[8];
  const float* Wout = (const float*)d_in[9];
  float* out = (float*)d_out;

  float* ws = (float*)d_ws;
  size_t o = 0;
  float* zbuf  = ws + o;  o += (size_t)ROWS * DI;                 // 25.2 MB
  float* xf    = ws + o;  o += (size_t)ROWS * DI;                 // 25.2 MB
  float* proj  = ws + o;  o += (size_t)Bb * Kk * LL * PROJ_C;     // 10.5 MB
  float* delta = ws + o;  o += (size_t)Bb * Kk * LL * DI;         // 50.3 MB
  const size_t hsz = (size_t)Bb * Kk * G * DI * Nn;               // 12.6 MB ea
  float* hend = ws + o;  o += hsz;
  float* Pst  = ws + o;  o += hsz;
  float* hini = ws + o;  o += hsz;
  float* y    = ws + o;  o += (size_t)Bb * DI * LL;               // 25.2 MB
  float* xc   = y;  // alias: xc dead after conv, before y is written

  k_xz<<<dim3(ROWS / 64, 3), 256, 0, stream>>>(x, Win, xc, zbuf);
  k_conv<<<dim3((Bb * Hh * 64 * 48) / 256), 256, 0, stream>>>(xc, cw, cb, xf);
  k_proj<<<dim3(ROWS / 64), 256, 0, stream>>>(xf, xpw, proj);
  k_delta<<<dim3((Bb * Kk * LL * 48) / 256), 256, 0, stream>>>(proj, dtw, dtb,
                                                               delta);
  k_scan<1, 0><<<dim3(Bb * G * 3), 256, 0, stream>>>(
      delta, proj, xf, Alog, Dsv, nullptr, hend, Pst, nullptr);
  k_scan<1, 1><<<dim3(Bb * G * 3), 256, 0, stream>>>(
      delta, proj, xf, Alog, Dsv, nullptr, hend, Pst, nullptr);
  k_scan2<<<dim3((Bb * Kk * DI * Nn) / 256), 256, 0, stream>>>(hend, Pst,
                                                               hini);
  k_scan<3, 0><<<dim3(Bb * G * 3), 256, 0, stream>>>(
      delta, proj, xf, Alog, Dsv, hini, nullptr, nullptr, y);
  k_scan<3, 1><<<dim3(Bb * G * 3), 256, 0, stream>>>(
      delta, proj, xf, Alog, Dsv, hini, nullptr, nullptr, y);
  k_out<<<dim3(ROWS / 128), 256, 0, stream>>>(y, zbuf, Wout, out);
}

// Round 8
// 333.737 us; speedup vs baseline: 1.3376x; 1.0514x over previous
//
#include <hip/hip_runtime.h>

// Problem constants
constexpr int Bb = 4, Hh = 32, Wd = 256, Cc = 96;
constexpr int DI = 192, Nn = 16, Rr = 6, Kk = 2;
constexpr int LL = Hh * Wd;          // 8192
constexpr int ROWS = Bb * LL;        // 32768
constexpr int PROJ_C = 40;           // [0..5]=dts, pad, [8..23]=B, [24..39]=C
constexpr int G = 128;               // scan chunks
constexpr int CH = LL / G;           // 64 steps per chunk
constexpr size_t YSZ = (size_t)Bb * DI * LL;  // one direction's y

static __device__ __forceinline__ float sigmoidf_(float v) {
  return 1.f / (1.f + __expf(-v));
}
static __device__ __forceinline__ float softplusf_(float v) {
  return v > 20.f ? v : __logf(1.f + __expf(v));
}

// ---------------------------------------------------------------------------
// Kernel 1: xz = x @ W_in^T  (32768 x 384, K=96). k_out-proven structure:
// 128row x 96col block tile, K chunked by 32, 4x12 reg tile, dk4-fast
// scatter staging (measured conflict-free in k_out/k_proj). Each 96-col
// block lands wholly in xc (blockIdx.y 0,1) or z (2,3) -> branch-free store.
// ---------------------------------------------------------------------------
__global__ __launch_bounds__(256) void k_xz(const float* __restrict__ x,
                                            const float* __restrict__ Win,
                                            float* __restrict__ xc,
                                            float* __restrict__ zbuf) {
  __shared__ float As[32][132];  // [k'][row]
  __shared__ float Ws[32][100];  // [k'][col]
  const int tid = threadIdx.x;
  const int row0 = blockIdx.x * 128;
  const int c0 = blockIdx.y * 96;
  const int tx = tid & 7;        // col = tx*12 + j
  const int ty = tid >> 3;       // row = ty*4 + i
  float acc[4][12] = {};

  for (int kc = 0; kc < 3; ++kc) {
    const int d0 = kc * 32;
    __syncthreads();
    for (int v = tid; v < 1024; v += 256) {
      const int l = v >> 3, dk4 = v & 7;
      const float4 xv =
          *(const float4*)&x[(size_t)(row0 + l) * 96 + d0 + dk4 * 4];
      As[dk4 * 4 + 0][l] = xv.x;
      As[dk4 * 4 + 1][l] = xv.y;
      As[dk4 * 4 + 2][l] = xv.z;
      As[dk4 * 4 + 3][l] = xv.w;
    }
    for (int v = tid; v < 768; v += 256) {
      const int c = v >> 3, dk4 = v & 7;
      const float4 wv =
          *(const float4*)&Win[(size_t)(c0 + c) * 96 + d0 + dk4 * 4];
      Ws[dk4 * 4 + 0][c] = wv.x;
      Ws[dk4 * 4 + 1][c] = wv.y;
      Ws[dk4 * 4 + 2][c] = wv.z;
      Ws[dk4 * 4 + 3][c] = wv.w;
    }
    __syncthreads();
    for (int dk = 0; dk < 32; ++dk) {
      const float4 a4 = *(const float4*)&As[dk][ty * 4];
      const float4 w0 = *(const float4*)&Ws[dk][tx * 12];
      const float4 w1 = *(const float4*)&Ws[dk][tx * 12 + 4];
      const float4 w2 = *(const float4*)&Ws[dk][tx * 12 + 8];
      const float av[4] = {a4.x, a4.y, a4.z, a4.w};
      const float wv[12] = {w0.x, w0.y, w0.z, w0.w, w1.x, w1.y,
                            w1.z, w1.w, w2.x, w2.y, w2.z, w2.w};
#pragma unroll
      for (int i = 0; i < 4; ++i)
#pragma unroll
        for (int j = 0; j < 12; ++j)
          acc[i][j] = fmaf(av[i], wv[j], acc[i][j]);
    }
  }

  float* dst;
  int cc0;
  if (c0 < DI) { dst = xc; cc0 = c0; }
  else         { dst = zbuf; cc0 = c0 - DI; }
#pragma unroll
  for (int i = 0; i < 4; ++i) {
    float* op = dst + (size_t)(row0 + ty * 4 + i) * DI + cc0 + tx * 12;
    *(float4*)(op + 0) = make_float4(acc[i][0], acc[i][1], acc[i][2], acc[i][3]);
    *(float4*)(op + 4) = make_float4(acc[i][4], acc[i][5], acc[i][6], acc[i][7]);
    *(float4*)(op + 8) = make_float4(acc[i][8], acc[i][9], acc[i][10], acc[i][11]);
  }
}

// ---------------------------------------------------------------------------
// Kernel 2: depthwise 3x3 conv + bias + SiLU. Branch-free, 18 unconditional
// masked halo loads, weights transposed in LDS.
// ---------------------------------------------------------------------------
__global__ __launch_bounds__(256) void k_conv(const float* __restrict__ xc,
                                              const float* __restrict__ cw,
                                              const float* __restrict__ cbias,
                                              float* __restrict__ xf) {
  __shared__ float wl[9 * DI];   // [tap][d]
  __shared__ float bl[DI];
  const int tid = threadIdx.x;
  for (int v = tid; v < 9 * DI; v += 256) {
    int dd = v / 9, t = v % 9;
    wl[t * DI + dd] = cw[v];
  }
  if (tid < DI) bl[tid] = cbias[tid];
  __syncthreads();

  int gid = blockIdx.x * 256 + tid;  // (b, h, w4, d4), d4 fast
  int d4 = gid % 48;
  int rem = gid / 48;
  int w4 = rem % 64;
  int bh = rem / 64;
  int h = bh % Hh, b = bh / Hh;
  const int d0 = d4 * 4, w0 = w4 * 4;

  float4 c[3][6];
#pragma unroll
  for (int dr = 0; dr < 3; ++dr) {
    const int h2 = h + dr - 1;
    const bool hv = (unsigned)h2 < (unsigned)Hh;
    const int hc = hv ? h2 : h;
    const float* rp = xc + ((size_t)(b * LL + (hc << 8))) * DI + d0;
#pragma unroll
    for (int j = 0; j < 6; ++j) {
      const int wc = w0 - 1 + j;
      const bool wv = (unsigned)wc < (unsigned)Wd;
      const int wcc = wv ? wc : w0;
      float4 v = *(const float4*)&rp[(size_t)wcc * DI];
      const float m = (hv && wv) ? 1.f : 0.f;
      c[dr][j] = make_float4(v.x * m, v.y * m, v.z * m, v.w * m);
    }
  }

  float4 wv9[9];
#pragma unroll
  for (int t = 0; t < 9; ++t) wv9[t] = *(const float4*)&wl[t * DI + d0];
  const float4 bias4 = *(const float4*)&bl[d0];

#pragma unroll
  for (int wi = 0; wi < 4; ++wi) {
    float4 a = bias4;
#pragma unroll
    for (int dr = 0; dr < 3; ++dr)
#pragma unroll
      for (int dc = 0; dc < 3; ++dc) {
        const float4 vv = c[dr][wi + dc];
        const float4 ww = wv9[dr * 3 + dc];
        a.x = fmaf(vv.x, ww.x, a.x);
        a.y = fmaf(vv.y, ww.y, a.y);
        a.z = fmaf(vv.z, ww.z, a.z);
        a.w = fmaf(vv.w, ww.w, a.w);
      }
    float4 r;
    r.x = a.x * sigmoidf_(a.x);
    r.y = a.y * sigmoidf_(a.y);
    r.z = a.z * sigmoidf_(a.z);
    r.w = a.w * sigmoidf_(a.w);
    *(float4*)&xf[((size_t)(b * LL + (h << 8) + w0 + wi)) * DI + d0] = r;
  }
}

// ---------------------------------------------------------------------------
// Kernel 3: x_dbl projections. Register-tiled GEMM, 64l x 80s tile, 4x5 reg.
// ---------------------------------------------------------------------------
__global__ __launch_bounds__(256) void k_proj(const float* __restrict__ xf,
                                              const float* __restrict__ xpw,
                                              float* __restrict__ proj) {
  __shared__ float smem[5376];     // As[32][68] | Ws[32][84]; reused as res[64][84]
  float* As = smem;
  float* Ws = smem + 32 * 68;
  const int tid = threadIdx.x;
  const int row0 = blockIdx.x * 64;
  const int b = row0 >> 13;
  const int l0 = row0 & (LL - 1);
  const int tx = tid & 15;
  const int ty = tid >> 4;
  float acc[4][5] = {};

  for (int kc = 0; kc < 6; ++kc) {
    const int d0 = kc * 32;
    __syncthreads();
    for (int v = tid; v < 512; v += 256) {
      const int l = v >> 3, dk4 = v & 7;
      const float4 xv =
          *(const float4*)&xf[((size_t)b * LL + l0 + l) * DI + d0 + dk4 * 4];
      As[(dk4 * 4 + 0) * 68 + l] = xv.x;
      As[(dk4 * 4 + 1) * 68 + l] = xv.y;
      As[(dk4 * 4 + 2) * 68 + l] = xv.z;
      As[(dk4 * 4 + 3) * 68 + l] = xv.w;
    }
    for (int v = tid; v < 640; v += 256) {
      const int s = v >> 3, dk4 = v & 7;
      const int k = s / 40, off = s % 40;
      float4 wv = make_float4(0.f, 0.f, 0.f, 0.f);
      if (off < 6 || off >= 8) {
        const int c = off < 6 ? off : off - 2;
        wv = *(const float4*)&xpw[(size_t)(k * 38 + c) * DI + d0 + dk4 * 4];
      }
      Ws[(dk4 * 4 + 0) * 84 + s] = wv.x;
      Ws[(dk4 * 4 + 1) * 84 + s] = wv.y;
      Ws[(dk4 * 4 + 2) * 84 + s] = wv.z;
      Ws[(dk4 * 4 + 3) * 84 + s] = wv.w;
    }
    __syncthreads();
    for (int dk = 0; dk < 32; ++dk) {
      const float4 a4 = *(const float4*)&As[dk * 68 + ty * 4];
      float w[5];
#pragma unroll
      for (int j = 0; j < 5; ++j) w[j] = Ws[dk * 84 + tx * 5 + j];
      const float av[4] = {a4.x, a4.y, a4.z, a4.w};
#pragma unroll
      for (int i = 0; i < 4; ++i)
#pragma unroll
        for (int j = 0; j < 5; ++j)
          acc[i][j] = fmaf(av[i], w[j], acc[i][j]);
    }
  }

  __syncthreads();
  float* res = smem;  // [64][84]
#pragma unroll
  for (int i = 0; i < 4; ++i)
#pragma unroll
    for (int j = 0; j < 5; ++j)
      res[(ty * 4 + i) * 84 + tx * 5 + j] = acc[i][j];
  __syncthreads();
#pragma unroll
  for (int k = 0; k < 2; ++k) {
    float* dst = proj + ((size_t)(b * Kk + k) * LL + l0) * PROJ_C;
    for (int v = tid; v < 640; v += 256) {
      const int l = v / 10, q = v % 10;
      *(float4*)&dst[l * PROJ_C + q * 4] =
          *(const float4*)&res[l * 84 + k * 40 + q * 4];
    }
  }
}

// ---------------------------------------------------------------------------
// Kernel 4: delta[b,k,l,d] = softplus(dts_r . dtw + bias), float4 over d.
// ---------------------------------------------------------------------------
__global__ __launch_bounds__(256) void k_delta(const float* __restrict__ proj,
                                               const float* __restrict__ dtw_,
                                               const float* __restrict__ dtb_,
                                               float* __restrict__ delta) {
  int gid = blockIdx.x * 256 + threadIdx.x;
  int d4 = gid % 48;
  int rem = gid / 48;
  int l = rem % LL;
  int bk = rem / LL;
  int k = bk & 1;
  const float* pr = proj + (size_t)(bk * LL + l) * PROJ_C;
  float p[6];
#pragma unroll
  for (int r = 0; r < 6; ++r) p[r] = pr[r];
  float4 res;
#pragma unroll
  for (int j = 0; j < 4; ++j) {
    int kd = k * DI + d4 * 4 + j;
    const float* w6 = dtw_ + (size_t)kd * 6;
    float draw = dtb_[kd];
#pragma unroll
    for (int r = 0; r < 6; ++r) draw = fmaf(p[r], w6[r], draw);
    ((float*)&res)[j] = softplusf_(draw);
  }
  *(float4*)&delta[(size_t)(bk * LL + l) * DI + d4 * 4] = res;
}

// ---------------------------------------------------------------------------
// Scan kernels. Both directions in ONE launch (runtime kdir decode; R5
// verified correctness of this decode). No atomics: pass3 kdir=0 writes y0,
// kdir=1 writes y1 (disjoint buffers); k_out sums them. 1-step software
// pipeline. PASS 1: h from 0 -> hend, P=exp(A*sum d). PASS 3: h from hinit.
// ---------------------------------------------------------------------------
template <int PASS>
__global__ __launch_bounds__(256) void k_scan(
    const float* __restrict__ delta, const float* __restrict__ proj,
    const float* __restrict__ xf, const float* __restrict__ Alog,
    const float* __restrict__ Dsv, const float* __restrict__ hinit,
    float* __restrict__ hend, float* __restrict__ Pst,
    float* __restrict__ yout) {
  const int tid = threadIdx.x;
  const int sub = tid & 3, gi = tid >> 2;
  int rest = blockIdx.x;
  const int kdir = rest & 1;  rest >>= 1;
  const int dt3 = rest % 3;   rest /= 3;
  const int g = rest % G;
  const int b = rest / G;
  const int d = dt3 * 64 + gi;
  const int kd = kdir * DI + d;
  const int bk = b * Kk + kdir;

  float A[4];
#pragma unroll
  for (int i = 0; i < 4; ++i) A[i] = -__expf(Alog[kd * 16 + sub * 4 + i]);

  const size_t gidx = (((size_t)(bk * G + g)) * DI + d) * Nn + sub * 4;
  float h[4];
  if (PASS == 1) {
    h[0] = h[1] = h[2] = h[3] = 0.f;
  } else {
    float4 h4 = *(const float4*)&hinit[gidx];
    h[0] = h4.x; h[1] = h4.y; h[2] = h4.z; h[3] = h4.w;
  }
  const float Dv = (PASS == 3) ? Dsv[kd] : 0.f;

  const int stp = kdir ? -1 : 1;
  const int dstp = stp * DI, pstp = stp * PROJ_C;
  const int l_start = kdir ? (LL - 1 - g * CH) : (g * CH);
  const float* dp = delta + ((size_t)bk * LL + l_start) * DI + d;
  const float* up = xf + ((size_t)b * LL + l_start) * DI + d;
  const float* pp = proj + ((size_t)bk * LL + l_start) * PROJ_C + 8 + sub * 4;
  float* yb = yout + (size_t)kdir * YSZ;
  const size_t ybase = ((size_t)b * DI + d) * LL;

  // pipeline primer
  float dlt_c = *dp;
  float u_c = *up;
  float4 B_c = *(const float4*)pp;
  float4 C_c;
  if (PASS == 3) C_c = *(const float4*)(pp + 16);

  float dsum = 0.f, ybuf = 0.f;
#pragma unroll 4
  for (int t = 0; t < CH; ++t) {
    dp += dstp; up += dstp; pp += pstp;
    const float dlt_n = *dp;   // prefetch (1-row overread on last iter, ok)
    const float u_n = *up;
    const float4 B_n = *(const float4*)pp;
    float4 C_n;
    if (PASS == 3) C_n = *(const float4*)(pp + 16);

    const float du = dlt_c * u_c;
    if (PASS == 1) {
#pragma unroll
      for (int i = 0; i < 4; ++i)
        h[i] = fmaf(__expf(dlt_c * A[i]), h[i], du * ((const float*)&B_c)[i]);
      dsum += dlt_c;
    } else {
      float yp = 0.f;
#pragma unroll
      for (int i = 0; i < 4; ++i) {
        h[i] = fmaf(__expf(dlt_c * A[i]), h[i], du * ((const float*)&B_c)[i]);
        yp = fmaf(h[i], ((const float*)&C_c)[i], yp);
      }
      yp += __shfl_xor(yp, 1, 64);
      yp += __shfl_xor(yp, 2, 64);
      const float yt = fmaf(u_c, Dv, yp);
      ybuf = ((t & 3) == sub) ? yt : ybuf;
      if ((t & 3) == 3) {
        const int tau = g * CH + (t & ~3) + sub;
        const int lp = kdir ? (LL - 1 - tau) : tau;
        yb[ybase + lp] = ybuf;
      }
    }
    dlt_c = dlt_n; u_c = u_n; B_c = B_n;
    if (PASS == 3) C_c = C_n;
  }
  if (PASS == 1) {
    float4 hv = make_float4(h[0], h[1], h[2], h[3]);
    float4 pv = make_float4(__expf(A[0] * dsum), __expf(A[1] * dsum),
                            __expf(A[2] * dsum), __expf(A[3] * dsum));
    *(float4*)&hend[gidx] = hv;
    *(float4*)&Pst[gidx] = pv;
  }
}

// Pass 2: combine chunk summaries sequentially per (b,k,d,n).
__global__ __launch_bounds__(256) void k_scan2(const float* __restrict__ hend,
                                               const float* __restrict__ Pst,
                                               float* __restrict__ hini) {
  int idx = blockIdx.x * 256 + threadIdx.x;
  int n = idx & 15;
  int rem = idx >> 4;
  int d = rem % DI;
  int bk = rem / DI;
  float carry = 0.f;
#pragma unroll 8
  for (int g = 0; g < G; ++g) {
    size_t a = (((size_t)(bk * G + g)) * DI + d) * Nn + n;
    float hv = hend[a], pv = Pst[a];
    hini[a] = carry;
    carry = fmaf(pv, carry, hv);
  }
}

// ---------------------------------------------------------------------------
// Kernel 7: out[l,c] = sum_d ((y0+y1)[b,d,l]*silu(z[b,l,d])) * Wout[c,d]
// Register-tiled GEMM: 128l x 96c block tile, K chunked by 32, 4x12 reg tile.
// ---------------------------------------------------------------------------
__global__ __launch_bounds__(256) void k_out(const float* __restrict__ y,
                                             const float* __restrict__ zbuf,
                                             const float* __restrict__ Wout,
                                             float* __restrict__ out) {
  __shared__ float As[32][132];
  __shared__ float Ws[32][100];
  const int tid = threadIdx.x;
  const int row0 = blockIdx.x * 128;
  const int b = row0 >> 13;
  const int l0 = row0 & (LL - 1);
  const int tx = tid & 7;
  const int ty = tid >> 3;
  float acc[4][12] = {};

  for (int kc = 0; kc < 6; ++kc) {
    const int d0 = kc * 32;
    __syncthreads();
    for (int v = tid; v < 1024; v += 256) {
      const int l = v >> 3, dk4 = v & 7;
      const float4 zv = *(const float4*)&zbuf[((size_t)b * LL + l0 + l) * DI +
                                              d0 + dk4 * 4];
      As[dk4 * 4 + 0][l] = zv.x * sigmoidf_(zv.x);
      As[dk4 * 4 + 1][l] = zv.y * sigmoidf_(zv.y);
      As[dk4 * 4 + 2][l] = zv.z * sigmoidf_(zv.z);
      As[dk4 * 4 + 3][l] = zv.w * sigmoidf_(zv.w);
    }
    for (int v = tid; v < 768; v += 256) {
      const int c = v >> 3, dk4 = v & 7;
      const float4 wv = *(const float4*)&Wout[(size_t)c * DI + d0 + dk4 * 4];
      Ws[dk4 * 4 + 0][c] = wv.x;
      Ws[dk4 * 4 + 1][c] = wv.y;
      Ws[dk4 * 4 + 2][c] = wv.z;
      Ws[dk4 * 4 + 3][c] = wv.w;
    }
    __syncthreads();
    for (int v = tid; v < 1024; v += 256) {
      const int dk = v >> 5, l4 = v & 31;
      const size_t yi = ((size_t)b * DI + d0 + dk) * LL + l0 + l4 * 4;
      const float4 y0v = *(const float4*)&y[yi];
      const float4 y1v = *(const float4*)&y[YSZ + yi];
      As[dk][l4 * 4 + 0] *= y0v.x + y1v.x;
      As[dk][l4 * 4 + 1] *= y0v.y + y1v.y;
      As[dk][l4 * 4 + 2] *= y0v.z + y1v.z;
      As[dk][l4 * 4 + 3] *= y0v.w + y1v.w;
    }
    __syncthreads();
    for (int dk = 0; dk < 32; ++dk) {
      const float4 a4 = *(const float4*)&As[dk][ty * 4];
      const float4 w0 = *(const float4*)&Ws[dk][tx * 12];
      const float4 w1 = *(const float4*)&Ws[dk][tx * 12 + 4];
      const float4 w2 = *(const float4*)&Ws[dk][tx * 12 + 8];
      const float av[4] = {a4.x, a4.y, a4.z, a4.w};
      const float wv[12] = {w0.x, w0.y, w0.z, w0.w, w1.x, w1.y,
                            w1.z, w1.w, w2.x, w2.y, w2.z, w2.w};
#pragma unroll
      for (int i = 0; i < 4; ++i)
#pragma unroll
        for (int j = 0; j < 12; ++j)
          acc[i][j] = fmaf(av[i], wv[j], acc[i][j]);
    }
  }

#pragma unroll
  for (int i = 0; i < 4; ++i) {
    float* op = out + ((size_t)b * LL + l0 + ty * 4 + i) * 96 + tx * 12;
    *(float4*)(op + 0) = make_float4(acc[i][0], acc[i][1], acc[i][2], acc[i][3]);
    *(float4*)(op + 4) = make_float4(acc[i][4], acc[i][5], acc[i][6], acc[i][7]);
    *(float4*)(op + 8) = make_float4(acc[i][8], acc[i][9], acc[i][10], acc[i][11]);
  }
}

// ---------------------------------------------------------------------------
extern "C" void kernel_launch(void* const* d_in, const int* in_sizes, int n_in,
                              void* d_out, int out_size, void* d_ws,
                              size_t ws_size, hipStream_t stream) {
  const float* x    = (const float*)d_in[0];
  const float* Win  = (const float*)d_in[1];
  const float* cw   = (const float*)d_in[2];
  const float* cb   = (const float*)d_in[3];
  const float* xpw  = (const float*)d_in[4];
  const float* dtw  = (const float*)d_in[5];
  const float* dtb  = (const float*)d_in[6];
  const float* Alog = (const float*)d_in[7];
  const float* Dsv  = (const float*)d_in[8];
  const float* Wout = (const float*)d_in[9];
  float* out = (float*)d_out;

  float* ws = (float*)d_ws;
  size_t o = 0;
  float* zbuf  = ws + o;  o += (size_t)ROWS * DI;                 // 25.2 MB
  float* xf    = ws + o;  o += (size_t)ROWS * DI;                 // 25.2 MB
  float* proj  = ws + o;  o += (size_t)Bb * Kk * LL * PROJ_C;     // 10.5 MB
  float* delta = ws + o;  o += (size_t)Bb * Kk * LL * DI;         // 50.3 MB
  const size_t hsz = (size_t)Bb * Kk * G * DI * Nn;               // 12.6 MB ea
  float* hend = ws + o;  o += hsz;
  float* Pst  = ws + o;  o += hsz;
  float* hini = ws + o;  o += hsz;
  float* y    = ws + o;  o += 2 * YSZ;                            // y0|y1, 50.3 MB
  float* xc   = y;  // alias: xc dead after conv, before y is written

  k_xz<<<dim3(ROWS / 128, 4), 256, 0, stream>>>(x, Win, xc, zbuf);
  k_conv<<<dim3((Bb * Hh * 64 * 48) / 256), 256, 0, stream>>>(xc, cw, cb, xf);
  k_proj<<<dim3(ROWS / 64), 256, 0, stream>>>(xf, xpw, proj);
  k_delta<<<dim3((Bb * Kk * LL * 48) / 256), 256, 0, stream>>>(proj, dtw, dtb,
                                                               delta);
  k_scan<1><<<dim3(Bb * G * 3 * 2), 256, 0, stream>>>(
      delta, proj, xf, Alog, Dsv, nullptr, hend, Pst, nullptr);
  k_scan2<<<dim3((Bb * Kk * DI * Nn) / 256), 256, 0, stream>>>(hend, Pst,
                                                               hini);
  k_scan<3><<<dim3(Bb * G * 3 * 2), 256, 0, stream>>>(
      delta, proj, xf, Alog, Dsv, hini, nullptr, nullptr, y);
  k_out<<<dim3(ROWS / 128), 256, 0, stream>>>(y, zbuf, Wout, out);
}